// Round 5
// baseline (310.657 us; speedup 1.0000x reference)
//
#include <hip/hip_runtime.h>

#define NCLS  32
#define SOS   30
#define EOS   31
#define LOG2E 1.4426950408889634f
#define LN2   0.6931471805599453f

typedef __attribute__((ext_vector_type(8))) short short8;
typedef __attribute__((ext_vector_type(4))) float f32x4;

__device__ __forceinline__ uint32_t rne_bf16(float x) {
    uint32_t u = __float_as_uint(x);
    return (u + 0x7fffu + ((u >> 16) & 1u)) >> 16;
}

// MFMA CRF forward, linear domain, ZERO cross-lane ops in the serial chain.
//
// Key trick vs round 4 (which burned 2 LDS latencies/step on a transpose):
// permute the classes across A's rows so D-layout == next step's B-layout.
//   A1 row m := ET[class 8*(m>>2)+(m&3)],  A2 row m := ET[class 8*(m>>2)+4+(m&3)]
// Then lane (q = lane>>4, n0 = lane&15) receives D1 = classes 8q..8q+3 and
// D2 = classes 8q+4..8q+7 of batch n0 — exactly the B-fragment rows
// B[k=8q+j][n=n0] it must supply next step. Chain per step:
//   4x v_perm (bf16 pack) -> 2x mfma_f32_16x16x32_bf16 -> 8x v_mul + 8x cndmask.
// ef = 2^(feat*log2e + mT[c] - 6) prefetched off-chain (ring depth 8 raw / 2 conv).
// Renorm every 4 steps: exact power-of-2 scale from class-0 exponent
// (per-batch uniform via one shfl), accumulated into C. Mask-applied step
// count tracked in cnt (handles mask=0 correctly, unlike round 4's 6*S).
__global__ __launch_bounds__(64, 1) void crf_fwd(const float* __restrict__ feats,
                                                 const float* __restrict__ mask,
                                                 const float* __restrict__ trans,
                                                 float* __restrict__ out,
                                                 int S, int B) {
    __shared__ float mts[NCLS];

    const int lane = threadIdx.x;      // one wave per block
    const int q  = lane >> 4;
    const int n0 = lane & 15;
    const int b  = blockIdx.x * 16 + n0;
    const int bb = (b < B) ? b : (B - 1);
    const int k0 = q * 8;              // this lane's class/k range: k0..k0+7

    // ---- one-time: per-class row max of That (log2-scaled) via LDS ----
    if (lane < NCLS) {
        float mx = -3.4e38f;
        #pragma unroll
        for (int k = 0; k < NCLS; ++k) mx = fmaxf(mx, trans[lane * NCLS + k]);
        mts[lane] = mx * LOG2E;
    }
    __builtin_amdgcn_wave_barrier();

    // ---- A fragments, class-permuted (see header) ----
    const int c1 = ((n0 >> 2) << 3) | (n0 & 3);
    const int c2 = c1 + 4;
    const float mc1 = mts[c1], mc2 = mts[c2];
    union { uint32_t u[4]; short8 s; } a1u, a2u;
    #pragma unroll
    for (int j2 = 0; j2 < 4; ++j2) {
        float f0 = __builtin_amdgcn_exp2f(trans[c1 * NCLS + k0 + 2*j2    ] * LOG2E - mc1);
        float f1 = __builtin_amdgcn_exp2f(trans[c1 * NCLS + k0 + 2*j2 + 1] * LOG2E - mc1);
        a1u.u[j2] = rne_bf16(f0) | (rne_bf16(f1) << 16);
        float g0 = __builtin_amdgcn_exp2f(trans[c2 * NCLS + k0 + 2*j2    ] * LOG2E - mc2);
        float g1 = __builtin_amdgcn_exp2f(trans[c2 * NCLS + k0 + 2*j2 + 1] * LOG2E - mc2);
        a2u.u[j2] = rne_bf16(g0) | (rne_bf16(g1) << 16);
    }
    const short8 a1 = a1u.s, a2 = a2u.s;

    // ---- ef exponent offsets + EOS factors for classes k0..k0+7 ----
    const float mtAx = mts[k0+0] - 6.f, mtAy = mts[k0+1] - 6.f;
    const float mtAz = mts[k0+2] - 6.f, mtAw = mts[k0+3] - 6.f;
    const float mtBx = mts[k0+4] - 6.f, mtBy = mts[k0+5] - 6.f;
    const float mtBz = mts[k0+6] - 6.f, mtBw = mts[k0+7] - 6.f;
    const float eos0 = __builtin_amdgcn_exp2f(trans[EOS * NCLS + k0 + 0] * LOG2E);
    const float eos1 = __builtin_amdgcn_exp2f(trans[EOS * NCLS + k0 + 1] * LOG2E);
    const float eos2 = __builtin_amdgcn_exp2f(trans[EOS * NCLS + k0 + 2] * LOG2E);
    const float eos3 = __builtin_amdgcn_exp2f(trans[EOS * NCLS + k0 + 3] * LOG2E);
    const float eos4 = __builtin_amdgcn_exp2f(trans[EOS * NCLS + k0 + 4] * LOG2E);
    const float eos5 = __builtin_amdgcn_exp2f(trans[EOS * NCLS + k0 + 5] * LOG2E);
    const float eos6 = __builtin_amdgcn_exp2f(trans[EOS * NCLS + k0 + 6] * LOG2E);
    const float eos7 = __builtin_amdgcn_exp2f(trans[EOS * NCLS + k0 + 7] * LOG2E);

    // ---- E init: 2^alpha0 -> 1 at SOS(=30, lane q=3 reg E2z), else 0 ----
    float E1x = 0.f, E1y = 0.f, E1z = 0.f, E1w = 0.f;
    float E2x = 0.f, E2y = 0.f, E2z = 0.f, E2w = 0.f;
    if (q == 3) E2z = 1.0f;
    float C = 0.f, cnt = 0.f;

    const size_t fstep = (size_t)B * NCLS;
    const float* fptr = feats + (size_t)bb * NCLS + k0;

#define LOADSLOT(Rf1, Rf2, Rm, T) {                                          \
        const float* _p = fptr + (size_t)(T) * fstep;                        \
        Rf1 = *(const float4*)_p;                                            \
        Rf2 = *(const float4*)(_p + 4);                                      \
        Rm  = mask[(size_t)(T) * B + bb];                                    \
    }

#define CONV(Rf1, Rf2, Rm, Ea, Eb, Md) {                                     \
        Ea.x = __builtin_amdgcn_exp2f(fmaf(Rf1.x, LOG2E, mtAx));             \
        Ea.y = __builtin_amdgcn_exp2f(fmaf(Rf1.y, LOG2E, mtAy));             \
        Ea.z = __builtin_amdgcn_exp2f(fmaf(Rf1.z, LOG2E, mtAz));             \
        Ea.w = __builtin_amdgcn_exp2f(fmaf(Rf1.w, LOG2E, mtAw));             \
        Eb.x = __builtin_amdgcn_exp2f(fmaf(Rf2.x, LOG2E, mtBx));             \
        Eb.y = __builtin_amdgcn_exp2f(fmaf(Rf2.y, LOG2E, mtBy));             \
        Eb.z = __builtin_amdgcn_exp2f(fmaf(Rf2.z, LOG2E, mtBz));             \
        Eb.w = __builtin_amdgcn_exp2f(fmaf(Rf2.w, LOG2E, mtBw));             \
        Md = Rm;                                                             \
    }

#define STEPCHAIN(EFa, EFb, EM, RENORM) {                                    \
        uint32_t p0 = __builtin_amdgcn_perm(__float_as_uint(E1y), __float_as_uint(E1x), 0x07060302u); \
        uint32_t p1 = __builtin_amdgcn_perm(__float_as_uint(E1w), __float_as_uint(E1z), 0x07060302u); \
        uint32_t p2 = __builtin_amdgcn_perm(__float_as_uint(E2y), __float_as_uint(E2x), 0x07060302u); \
        uint32_t p3 = __builtin_amdgcn_perm(__float_as_uint(E2w), __float_as_uint(E2z), 0x07060302u); \
        union { uint32_t u[4]; short8 s; } _bu;                              \
        _bu.u[0] = p0; _bu.u[1] = p1; _bu.u[2] = p2; _bu.u[3] = p3;          \
        f32x4 _z = {0.f, 0.f, 0.f, 0.f};                                     \
        f32x4 _d1 = __builtin_amdgcn_mfma_f32_16x16x32_bf16(a1, _bu.s, _z, 0, 0, 0); \
        f32x4 _d2 = __builtin_amdgcn_mfma_f32_16x16x32_bf16(a2, _bu.s, _z, 0, 0, 0); \
        bool _sel = (EM != 0.0f);                                            \
        E1x = _sel ? _d1[0] * EFa.x : E1x;  E1y = _sel ? _d1[1] * EFa.y : E1y; \
        E1z = _sel ? _d1[2] * EFa.z : E1z;  E1w = _sel ? _d1[3] * EFa.w : E1w; \
        E2x = _sel ? _d2[0] * EFb.x : E2x;  E2y = _sel ? _d2[1] * EFb.y : E2y; \
        E2z = _sel ? _d2[2] * EFb.z : E2z;  E2w = _sel ? _d2[3] * EFb.w : E2w; \
        cnt += EM;                                                           \
        if (RENORM) {                                                        \
            float _Dv = __shfl(E1x, n0, 64);   /* class 0 of this batch */   \
            uint32_t _eb = (__float_as_uint(_Dv) >> 23) & 0xffu;             \
            C += (float)((int)_eb - 127);                                    \
            float _sc = __uint_as_float((254u - _eb) << 23);                 \
            E1x *= _sc; E1y *= _sc; E1z *= _sc; E1w *= _sc;                  \
            E2x *= _sc; E2y *= _sc; E2z *= _sc; E2w *= _sc;                  \
        }                                                                    \
    }

// one pipeline unit: consume ef slot, refill it from raw slot (t+2), load raw (t+8)
#define UNIT(Ea, Eb, Em, Rc1, Rc2, Rcm, Rl1, Rl2, Rlm, T, RN)                \
        STEPCHAIN(Ea, Eb, Em, RN)                                            \
        CONV(Rc1, Rc2, Rcm, Ea, Eb, Em)                                      \
        LOADSLOT(Rl1, Rl2, Rlm, T)

    float4 r1_0, r1_1, r1_2, r1_3, r1_4, r1_5, r1_6, r1_7;
    float4 r2_0, r2_1, r2_2, r2_3, r2_4, r2_5, r2_6, r2_7;
    float  rm_0, rm_1, rm_2, rm_3, rm_4, rm_5, rm_6, rm_7;
    float4 e1_0, e2_0, e1_1, e2_1;
    float  m_0, m_1;

    const int Sm1 = S - 1;
    int tb = 0;

    if (S >= 16) {
        LOADSLOT(r1_0, r2_0, rm_0, 0); LOADSLOT(r1_1, r2_1, rm_1, 1);
        LOADSLOT(r1_2, r2_2, rm_2, 2); LOADSLOT(r1_3, r2_3, rm_3, 3);
        LOADSLOT(r1_4, r2_4, rm_4, 4); LOADSLOT(r1_5, r2_5, rm_5, 5);
        LOADSLOT(r1_6, r2_6, rm_6, 6); LOADSLOT(r1_7, r2_7, rm_7, 7);
        CONV(r1_0, r2_0, rm_0, e1_0, e2_0, m_0);
        CONV(r1_1, r2_1, rm_1, e1_1, e2_1, m_1);

        for (; tb + 16 <= S; tb += 8) {
            UNIT(e1_0, e2_0, m_0, r1_2, r2_2, rm_2, r1_0, r2_0, rm_0, tb +  8, false);
            UNIT(e1_1, e2_1, m_1, r1_3, r2_3, rm_3, r1_1, r2_1, rm_1, tb +  9, false);
            UNIT(e1_0, e2_0, m_0, r1_4, r2_4, rm_4, r1_2, r2_2, rm_2, tb + 10, false);
            UNIT(e1_1, e2_1, m_1, r1_5, r2_5, rm_5, r1_3, r2_3, rm_3, tb + 11, true);
            UNIT(e1_0, e2_0, m_0, r1_6, r2_6, rm_6, r1_4, r2_4, rm_4, tb + 12, false);
            UNIT(e1_1, e2_1, m_1, r1_7, r2_7, rm_7, r1_5, r2_5, rm_5, tb + 13, false);
            UNIT(e1_0, e2_0, m_0, r1_0, r2_0, rm_0, r1_6, r2_6, rm_6, tb + 14, false);
            UNIT(e1_1, e2_1, m_1, r1_1, r2_1, rm_1, r1_7, r2_7, rm_7, tb + 15, true);
        }
        // penultimate block of 8: loads are dead, clamp to Sm1
        {
            int ta = tb + 8 < Sm1 ? tb + 8 : Sm1;   (void)ta;
            UNIT(e1_0, e2_0, m_0, r1_2, r2_2, rm_2, r1_0, r2_0, rm_0, Sm1, false);
            UNIT(e1_1, e2_1, m_1, r1_3, r2_3, rm_3, r1_1, r2_1, rm_1, Sm1, false);
            UNIT(e1_0, e2_0, m_0, r1_4, r2_4, rm_4, r1_2, r2_2, rm_2, Sm1, false);
            UNIT(e1_1, e2_1, m_1, r1_5, r2_5, rm_5, r1_3, r2_3, rm_3, Sm1, true);
            UNIT(e1_0, e2_0, m_0, r1_6, r2_6, rm_6, r1_4, r2_4, rm_4, Sm1, false);
            UNIT(e1_1, e2_1, m_1, r1_7, r2_7, rm_7, r1_5, r2_5, rm_5, Sm1, false);
            UNIT(e1_0, e2_0, m_0, r1_0, r2_0, rm_0, r1_6, r2_6, rm_6, Sm1, false);
            UNIT(e1_1, e2_1, m_1, r1_1, r2_1, rm_1, r1_7, r2_7, rm_7, Sm1, true);
            tb += 8;
        }
    }
    // tail (and whole sequence when S < 16): direct per-step
    for (int t = tb; t < S; ++t) {
        float4 tf1, tf2; float tmv;
        LOADSLOT(tf1, tf2, tmv, t);
        float4 te1, te2; float tem;
        CONV(tf1, tf2, tmv, te1, te2, tem);
        const bool rn = ((t & 3) == 3);
        STEPCHAIN(te1, te2, tem, rn);
    }

    // ---- epilogue: out[b] = ln2*(C + 6*cnt + log2(sum_c E[c]*2^That[EOS][c])) ----
    float w = E1x * eos0 + E1y * eos1 + E1z * eos2 + E1w * eos3
            + E2x * eos4 + E2y * eos5 + E2z * eos6 + E2w * eos7;
    w += __shfl_xor(w, 16, 64);
    w += __shfl_xor(w, 32, 64);
    if (q == 0 && b < B) {
        out[b] = LN2 * (C + 6.0f * cnt + __builtin_amdgcn_logf(w));
    }
#undef LOADSLOT
#undef CONV
#undef STEPCHAIN
#undef UNIT
}

extern "C" void kernel_launch(void* const* d_in, const int* in_sizes, int n_in,
                              void* d_out, int out_size, void* d_ws, size_t ws_size,
                              hipStream_t stream) {
    const float* feats = (const float*)d_in[0];
    const float* mask  = (const float*)d_in[1];
    const float* trans = (const float*)d_in[2];
    float* out = (float*)d_out;

    const int B = out_size;            // batch  (2048)
    const int S = in_sizes[1] / B;     // seq_len (512)

    dim3 block(64);                    // one wave
    dim3 grid((B + 15) / 16);          // 16 batches per wave
    hipLaunchKernelGGL(crf_fwd, grid, block, 0, stream, feats, mask, trans, out, S, B);
}

// Round 7
// 225.414 us; speedup vs baseline: 1.3782x; 1.3782x over previous
//
#include <hip/hip_runtime.h>

#define NCLS  32
#define SOS   30
#define EOS   31
#define LOG2E 1.4426950408889634f
#define LN2   0.6931471805599453f

typedef __attribute__((ext_vector_type(8))) short short8;
typedef __attribute__((ext_vector_type(4))) float f32x4;

__device__ __forceinline__ uint32_t rne_bf16(float x) {
    uint32_t u = __float_as_uint(x);
    return (u + 0x7fffu + ((u >> 16) & 1u)) >> 16;
}

// Meet-in-the-middle MFMA CRF forward, linear domain.
//
//   out_b = ln( u^T M_S ... M_1 v0 ),  M_t = m_t ? diag(ef_t) X : I,
//   X[c,j] = 2^That[c,j],  u = 2^That[EOS,:],  v0 = e_SOS.
// Wave 0 (fwd): E_t = M_t E_{t-1}, rows 0..H-1.
// Wave 1 (bwd): wtil_{t-1}[j] = sum_c Y[j,c] * efb_t[c] * wtil_t[c], rows S-1..H,
//   Y[j,c] = 2^(That[c,j]-cms[j]) (col-max normalized), efb[c]=2^(fhat+cms[c]-6),
//   wtil_S[c] = 2^(That[EOS,c]-cms[c]); final factor 2^cms[j] applied at combine.
// Combine (LDS + syncthreads): out = LN2*(Cf+Cb+6(cntf+cntb)+log2(sum wtil*kc*E)).
//
// Both passes use the round-5 self-feeding MFMA trick (A rows class-permuted
// so D-layout == next step's B-fragment): zero cross-lane ops in the chain.
// 2 real batches/wave (8x lane mirror), fwd+bwd waves share a block:
// grid 1024 x 128 thr = 2048 waves = 2 waves/SIMD -> TLP hides chain latency
// (rounds 2-5 showed compiler won't keep a deep prefetch ring live; TLP is
// the robust backstop, no inline-asm pinning).
__global__ __launch_bounds__(128, 2) void crf_fwd(const float* __restrict__ feats,
                                                  const float* __restrict__ mask,
                                                  const float* __restrict__ trans,
                                                  float* __restrict__ out,
                                                  int S, int B) {
    __shared__ float mxs[2][NCLS];               // [0]=row max (fwd), [1]=col max (bwd)
    __shared__ __align__(16) float wsh[2][NCLS]; // combine vectors
    __shared__ float wsc[2];                     // combine scalars

    const int tid  = threadIdx.x;
    const int wid  = tid >> 6;        // 0 = forward wave, 1 = backward wave
    const int lane = tid & 63;
    const int q  = lane >> 4;
    const int n0 = lane & 15;
    const int k0 = q * 8;
    const int b  = blockIdx.x * 2 + (n0 & 1);
    const int bb = (b < B) ? b : (B - 1);

    // ---- per-class normalizers: fwd = row max, bwd = col max (log2-scaled) ----
    if (lane < NCLS) {
        float mx = -3.4e38f;
        #pragma unroll
        for (int k = 0; k < NCLS; ++k)
            mx = fmaxf(mx, wid ? trans[k * NCLS + lane] : trans[lane * NCLS + k]);
        mxs[wid][lane] = mx * LOG2E;
    }
    __builtin_amdgcn_wave_barrier();
    const float* mx_ = mxs[wid];

    // ---- A fragments, class-permuted so D-layout == next step's B-layout ----
    const int c1 = ((n0 >> 2) << 3) | (n0 & 3);
    const int c2 = c1 + 4;
    const float nc1 = mx_[c1], nc2 = mx_[c2];
    union { uint32_t u[4]; short8 s; } a1u, a2u;
    #pragma unroll
    for (int j2 = 0; j2 < 4; ++j2) {
        const int ka = k0 + 2 * j2, kb = ka + 1;
        float f0 = __builtin_amdgcn_exp2f((wid ? trans[ka*NCLS + c1] : trans[c1*NCLS + ka]) * LOG2E - nc1);
        float f1 = __builtin_amdgcn_exp2f((wid ? trans[kb*NCLS + c1] : trans[c1*NCLS + kb]) * LOG2E - nc1);
        a1u.u[j2] = rne_bf16(f0) | (rne_bf16(f1) << 16);
        float g0 = __builtin_amdgcn_exp2f((wid ? trans[ka*NCLS + c2] : trans[c2*NCLS + ka]) * LOG2E - nc2);
        float g1 = __builtin_amdgcn_exp2f((wid ? trans[kb*NCLS + c2] : trans[c2*NCLS + kb]) * LOG2E - nc2);
        a2u.u[j2] = rne_bf16(g0) | (rne_bf16(g1) << 16);
    }
    const short8 a1 = a1u.s, a2 = a2u.s;

    // ---- conversion biases for this lane's classes k0..k0+7 ----
    const float mtAx = mx_[k0+0] - 6.f, mtAy = mx_[k0+1] - 6.f;
    const float mtAz = mx_[k0+2] - 6.f, mtAw = mx_[k0+3] - 6.f;
    const float mtBx = mx_[k0+4] - 6.f, mtBy = mx_[k0+5] - 6.f;
    const float mtBz = mx_[k0+6] - 6.f, mtBw = mx_[k0+7] - 6.f;

    // ---- state init ----
    float E1x = 0.f, E1y = 0.f, E1z = 0.f, E1w = 0.f;
    float E2x = 0.f, E2y = 0.f, E2z = 0.f, E2w = 0.f;
    if (wid == 0) {
        if (q == 3) E2z = 1.0f;       // SOS = 30 = 8*3+6
    } else {
        E1x = __builtin_amdgcn_exp2f(trans[EOS*NCLS + k0+0] * LOG2E - mx_[k0+0]);
        E1y = __builtin_amdgcn_exp2f(trans[EOS*NCLS + k0+1] * LOG2E - mx_[k0+1]);
        E1z = __builtin_amdgcn_exp2f(trans[EOS*NCLS + k0+2] * LOG2E - mx_[k0+2]);
        E1w = __builtin_amdgcn_exp2f(trans[EOS*NCLS + k0+3] * LOG2E - mx_[k0+3]);
        E2x = __builtin_amdgcn_exp2f(trans[EOS*NCLS + k0+4] * LOG2E - mx_[k0+4]);
        E2y = __builtin_amdgcn_exp2f(trans[EOS*NCLS + k0+5] * LOG2E - mx_[k0+5]);
        E2z = __builtin_amdgcn_exp2f(trans[EOS*NCLS + k0+6] * LOG2E - mx_[k0+6]);
        E2w = __builtin_amdgcn_exp2f(trans[EOS*NCLS + k0+7] * LOG2E - mx_[k0+7]);
    }
    float C = 0.f, cnt = 0.f;

    // ---- direction setup ----
    const long long fstep = (long long)B * NCLS;
    const int Hf = (S + 1) >> 1;
    const int H  = wid ? (S - Hf) : Hf;
    const int r0 = wid ? (S - 1) : 0;
    const long long dstep = wid ? -fstep : fstep;
    const long long mstep = wid ? -(long long)B : (long long)B;
    const float* fbase = feats + (long long)r0 * fstep + (long long)bb * NCLS + k0;
    const float* mbase = mask + (long long)r0 * B + bb;

#define LOADSLOT(Rf1, Rf2, Rm, T) {                                          \
        const float* _p = fbase + (long long)(T) * dstep;                    \
        Rf1 = *(const f32x4*)_p;                                             \
        Rf2 = *(const f32x4*)(_p + 4);                                       \
        Rm  = mbase[(long long)(T) * mstep];                                 \
    }

#define CONV(Rf1, Rf2, Rm, Ea, Eb, Md) {                                     \
        Ea.x = __builtin_amdgcn_exp2f(fmaf(Rf1.x, LOG2E, mtAx));             \
        Ea.y = __builtin_amdgcn_exp2f(fmaf(Rf1.y, LOG2E, mtAy));             \
        Ea.z = __builtin_amdgcn_exp2f(fmaf(Rf1.z, LOG2E, mtAz));             \
        Ea.w = __builtin_amdgcn_exp2f(fmaf(Rf1.w, LOG2E, mtAw));             \
        Eb.x = __builtin_amdgcn_exp2f(fmaf(Rf2.x, LOG2E, mtBx));             \
        Eb.y = __builtin_amdgcn_exp2f(fmaf(Rf2.y, LOG2E, mtBy));             \
        Eb.z = __builtin_amdgcn_exp2f(fmaf(Rf2.z, LOG2E, mtBz));             \
        Eb.w = __builtin_amdgcn_exp2f(fmaf(Rf2.w, LOG2E, mtBw));             \
        Md = Rm;                                                             \
    }

#define RENORM_E {                                                           \
        float _Dv = __shfl(E1x, n0, 64);      /* class 0 of this batch */    \
        uint32_t _eb = (__float_as_uint(_Dv) >> 23) & 0xffu;                 \
        C += (float)((int)_eb - 127);                                        \
        float _sc = __uint_as_float((254u - _eb) << 23);                     \
        E1x *= _sc; E1y *= _sc; E1z *= _sc; E1w *= _sc;                      \
        E2x *= _sc; E2y *= _sc; E2z *= _sc; E2w *= _sc;                      \
    }

// fwd step: D = A*pack(E); E' = sel(ef .* D, E)
#define STEPF(EFa, EFb, EM, RN) {                                            \
        uint32_t p0 = __builtin_amdgcn_perm(__float_as_uint(E1y), __float_as_uint(E1x), 0x07060302u); \
        uint32_t p1 = __builtin_amdgcn_perm(__float_as_uint(E1w), __float_as_uint(E1z), 0x07060302u); \
        uint32_t p2 = __builtin_amdgcn_perm(__float_as_uint(E2y), __float_as_uint(E2x), 0x07060302u); \
        uint32_t p3 = __builtin_amdgcn_perm(__float_as_uint(E2w), __float_as_uint(E2z), 0x07060302u); \
        union { uint32_t u[4]; short8 s; } _bu;                              \
        _bu.u[0] = p0; _bu.u[1] = p1; _bu.u[2] = p2; _bu.u[3] = p3;          \
        const f32x4 _z = {0.f, 0.f, 0.f, 0.f};                               \
        f32x4 _d1 = __builtin_amdgcn_mfma_f32_16x16x32_bf16(a1, _bu.s, _z, 0, 0, 0); \
        f32x4 _d2 = __builtin_amdgcn_mfma_f32_16x16x32_bf16(a2, _bu.s, _z, 0, 0, 0); \
        const bool _s = (EM != 0.0f);                                        \
        E1x = _s ? _d1[0] * EFa.x : E1x;  E1y = _s ? _d1[1] * EFa.y : E1y;   \
        E1z = _s ? _d1[2] * EFa.z : E1z;  E1w = _s ? _d1[3] * EFa.w : E1w;   \
        E2x = _s ? _d2[0] * EFb.x : E2x;  E2y = _s ? _d2[1] * EFb.y : E2y;   \
        E2z = _s ? _d2[2] * EFb.z : E2z;  E2w = _s ? _d2[3] * EFb.w : E2w;   \
        cnt += EM;                                                           \
        if (RN) RENORM_E                                                     \
    }

// bwd step: t = ef .* w; D = A*pack(t); w' = sel(D, w)
#define STEPB(EFa, EFb, EM, RN) {                                            \
        float t1x = E1x * EFa.x, t1y = E1y * EFa.y, t1z = E1z * EFa.z, t1w = E1w * EFa.w; \
        float t2x = E2x * EFb.x, t2y = E2y * EFb.y, t2z = E2z * EFb.z, t2w = E2w * EFb.w; \
        uint32_t p0 = __builtin_amdgcn_perm(__float_as_uint(t1y), __float_as_uint(t1x), 0x07060302u); \
        uint32_t p1 = __builtin_amdgcn_perm(__float_as_uint(t1w), __float_as_uint(t1z), 0x07060302u); \
        uint32_t p2 = __builtin_amdgcn_perm(__float_as_uint(t2y), __float_as_uint(t2x), 0x07060302u); \
        uint32_t p3 = __builtin_amdgcn_perm(__float_as_uint(t2w), __float_as_uint(t2z), 0x07060302u); \
        union { uint32_t u[4]; short8 s; } _bu;                              \
        _bu.u[0] = p0; _bu.u[1] = p1; _bu.u[2] = p2; _bu.u[3] = p3;          \
        const f32x4 _z = {0.f, 0.f, 0.f, 0.f};                               \
        f32x4 _d1 = __builtin_amdgcn_mfma_f32_16x16x32_bf16(a1, _bu.s, _z, 0, 0, 0); \
        f32x4 _d2 = __builtin_amdgcn_mfma_f32_16x16x32_bf16(a2, _bu.s, _z, 0, 0, 0); \
        const bool _s = (EM != 0.0f);                                        \
        E1x = _s ? _d1[0] : E1x;  E1y = _s ? _d1[1] : E1y;                   \
        E1z = _s ? _d1[2] : E1z;  E1w = _s ? _d1[3] : E1w;                   \
        E2x = _s ? _d2[0] : E2x;  E2y = _s ? _d2[1] : E2y;                   \
        E2z = _s ? _d2[2] : E2z;  E2w = _s ? _d2[3] : E2w;                   \
        cnt += EM;                                                           \
        if (RN) RENORM_E                                                     \
    }

// raw ring depth 4, converted (ef) ring depth 2
#define PIPELINE(STEPM) {                                                    \
        f32x4 r1_0, r1_1, r1_2, r1_3, r2_0, r2_1, r2_2, r2_3;                \
        float rm_0, rm_1, rm_2, rm_3;                                        \
        f32x4 e1_0, e2_0, e1_1, e2_1;                                        \
        float m_0, m_1;                                                      \
        int tb = 0;                                                          \
        if (H >= 8) {                                                        \
            LOADSLOT(r1_0, r2_0, rm_0, 0); LOADSLOT(r1_1, r2_1, rm_1, 1);    \
            LOADSLOT(r1_2, r2_2, rm_2, 2); LOADSLOT(r1_3, r2_3, rm_3, 3);    \
            CONV(r1_0, r2_0, rm_0, e1_0, e2_0, m_0);                         \
            CONV(r1_1, r2_1, rm_1, e1_1, e2_1, m_1);                         \
            for (; tb + 8 <= H; tb += 4) {                                   \
                STEPM(e1_0, e2_0, m_0, false)                                \
                CONV(r1_2, r2_2, rm_2, e1_0, e2_0, m_0);                     \
                LOADSLOT(r1_0, r2_0, rm_0, tb + 4);                          \
                STEPM(e1_1, e2_1, m_1, false)                                \
                CONV(r1_3, r2_3, rm_3, e1_1, e2_1, m_1);                     \
                LOADSLOT(r1_1, r2_1, rm_1, tb + 5);                          \
                STEPM(e1_0, e2_0, m_0, false)                                \
                CONV(r1_0, r2_0, rm_0, e1_0, e2_0, m_0);                     \
                LOADSLOT(r1_2, r2_2, rm_2, tb + 6);                          \
                STEPM(e1_1, e2_1, m_1, true)                                 \
                CONV(r1_1, r2_1, rm_1, e1_1, e2_1, m_1);                     \
                LOADSLOT(r1_3, r2_3, rm_3, tb + 7);                          \
            }                                                                \
        }                                                                    \
        for (int t = tb; t < H; ++t) {      /* tail: fresh direct loads */   \
            f32x4 tf1, tf2; float tmr;                                       \
            LOADSLOT(tf1, tf2, tmr, t);                                      \
            f32x4 te1, te2; float tem;                                       \
            CONV(tf1, tf2, tmr, te1, te2, tem);                              \
            STEPM(te1, te2, tem, ((t & 3) == 3))                             \
        }                                                                    \
    }

    if (wid == 0) { PIPELINE(STEPF) } else { PIPELINE(STEPB) }

    // ---- combine: bwd publishes wtil*2^cms + scalar; fwd dots with E ----
    if (wid == 1) {
        if (n0 < 2) {
            wsh[n0][k0+0] = E1x * __builtin_amdgcn_exp2f(mx_[k0+0]);
            wsh[n0][k0+1] = E1y * __builtin_amdgcn_exp2f(mx_[k0+1]);
            wsh[n0][k0+2] = E1z * __builtin_amdgcn_exp2f(mx_[k0+2]);
            wsh[n0][k0+3] = E1w * __builtin_amdgcn_exp2f(mx_[k0+3]);
            wsh[n0][k0+4] = E2x * __builtin_amdgcn_exp2f(mx_[k0+4]);
            wsh[n0][k0+5] = E2y * __builtin_amdgcn_exp2f(mx_[k0+5]);
            wsh[n0][k0+6] = E2z * __builtin_amdgcn_exp2f(mx_[k0+6]);
            wsh[n0][k0+7] = E2w * __builtin_amdgcn_exp2f(mx_[k0+7]);
            if (q == 0) wsc[n0] = C + 6.0f * cnt;
        }
    }
    __syncthreads();
    if (wid == 0) {
        const int bc = n0 & 1;
        const f32x4 wa = *(const f32x4*)&wsh[bc][k0];
        const f32x4 wb = *(const f32x4*)&wsh[bc][k0 + 4];
        float dot = E1x * wa.x + E1y * wa.y + E1z * wa.z + E1w * wa.w
                  + E2x * wb.x + E2y * wb.y + E2z * wb.z + E2w * wb.w;
        dot += __shfl_xor(dot, 16, 64);
        dot += __shfl_xor(dot, 32, 64);
        if (q == 0 && n0 < 2 && b < B) {
            out[b] = LN2 * (C + 6.0f * cnt + wsc[bc] + __builtin_amdgcn_logf(dot));
        }
    }
#undef LOADSLOT
#undef CONV
#undef RENORM_E
#undef STEPF
#undef STEPB
#undef PIPELINE
}

extern "C" void kernel_launch(void* const* d_in, const int* in_sizes, int n_in,
                              void* d_out, int out_size, void* d_ws, size_t ws_size,
                              hipStream_t stream) {
    const float* feats = (const float*)d_in[0];
    const float* mask  = (const float*)d_in[1];
    const float* trans = (const float*)d_in[2];
    float* out = (float*)d_out;

    const int B = out_size;            // batch  (2048)
    const int S = in_sizes[1] / B;     // seq_len (512)

    dim3 block(128);                   // wave 0 = fwd, wave 1 = bwd
    dim3 grid((B + 1) / 2);            // 2 real batches per block -> 1024 blocks
    hipLaunchKernelGGL(crf_fwd, grid, block, 0, stream, feats, mask, trans, out, S, B);
}